// Round 18
// baseline (107.151 us; speedup 1.0000x reference)
//
#include <hip/hip_runtime.h>
#include <math.h>

#define N 4096
#define D 128
#define NROW 16               // rows per block
#define NBLKS 256             // main-kernel grid (one 16-row panel per block)
#define BIGV 1e30f
#define E1C  2.718281828459045f     // e^1  (mode-1 pos post-scale)
#define EM5C 0.006737946999085467f  // e^-5 (mode-1 neg post-scale)

typedef __bf16 bf16x8 __attribute__((ext_vector_type(8)));
typedef float  f32x4  __attribute__((ext_vector_type(4)));

__device__ __forceinline__ void stg(float* p, float v) {
  __hip_atomic_store(p, v, __ATOMIC_RELAXED, __HIP_MEMORY_SCOPE_AGENT);
}
__device__ __forceinline__ float ldg1(const float* p) {
  return __hip_atomic_load((float*)p, __ATOMIC_RELAXED, __HIP_MEMORY_SCOPE_AGENT);
}

// split 8 f32 -> 8 bf16 hi + 8 bf16 lo (rne/rne; proven bit-exact path)
__device__ __forceinline__ void cvt8(float4 v0, float4 v1, int4& hp, int4& lp) {
  float vf[8] = {v0.x, v0.y, v0.z, v0.w, v1.x, v1.y, v1.z, v1.w};
  unsigned h[8], l[8];
#pragma unroll
  for (int i = 0; i < 8; ++i) {
    unsigned u = __float_as_uint(vf[i]);
    unsigned hr = (u + 0x7FFFu + ((u >> 16) & 1u)) >> 16;
    float hv = __uint_as_float(hr << 16);
    unsigned ul = __float_as_uint(vf[i] - hv);
    l[i] = (ul + 0x7FFFu + ((ul >> 16) & 1u)) >> 16;
    h[i] = hr;
  }
  hp = make_int4((int)(h[0] | (h[1] << 16)), (int)(h[2] | (h[3] << 16)),
                 (int)(h[4] | (h[5] << 16)), (int)(h[6] | (h[7] << 16)));
  lp = make_int4((int)(l[0] | (l[1] << 16)), (int)(l[2] | (l[3] << 16)),
                 (int)(l[4] | (l[5] << 16)), (int)(l[6] | (l[7] << 16)));
}
__device__ __forceinline__ void cvt8hi(float4 v0, float4 v1, int4& hp) {
  float vf[8] = {v0.x, v0.y, v0.z, v0.w, v1.x, v1.y, v1.z, v1.w};
  unsigned h[8];
#pragma unroll
  for (int i = 0; i < 8; ++i) {
    unsigned u = __float_as_uint(vf[i]);
    h[i] = (u + 0x7FFFu + ((u >> 16) & 1u)) >> 16;
  }
  hp = make_int4((int)(h[0] | (h[1] << 16)), (int)(h[2] | (h[3] << 16)),
                 (int)(h[4] | (h[5] << 16)), (int)(h[6] | (h[7] << 16)));
}

// ---- convert kernel: x -> bf16-hi in MFMA-fragment-linear order ----
// unit = ((C>>4)*4 + (k16>>2))*64 + (k16&3)*16 + (C&15); 16B per unit.
__global__ __launch_bounds__(256)
void k_conv(const float* __restrict__ x, ushort* __restrict__ xf, unsigned* done)
{
  if (blockIdx.x == 0 && threadIdx.x == 0)
    __hip_atomic_store(done, 0u, __ATOMIC_RELAXED, __HIP_MEMORY_SCOPE_AGENT);
  int gid = blockIdx.x * 256 + threadIdx.x;     // 65536 = 4096 C x 16 k16
  int C = gid >> 4, k16 = gid & 15;
  const float* ap = x + C * D + k16 * 8;
  float4 v0 = *(const float4*)ap, v1 = *(const float4*)(ap + 4);
  int4 hp;
  cvt8hi(v0, v1, hp);
  int unit = ((C >> 4) * 4 + (k16 >> 2)) * 64 + (k16 & 3) * 16 + (C & 15);
  *(int4*)((char*)xf + ((size_t)unit << 4)) = hp;
}

// Transposed-attribution tile: a[jj] = sim[row = i0 + (l&15)][col = ct*16 + (l>>4)*4 + jj]
// (mfma operand swap is free: A- and B-operand fragments share the same lane layout.)
__device__ __forceinline__ f32x4 tile_sim(const ushort* __restrict__ xf,
                                          const bf16x8 (&Ah)[4], const bf16x8 (&Al)[4],
                                          int ct, int bid, int l)
{
  f32x4 a = f32x4{0.f, 0.f, 0.f, 0.f};
  if (ct == bid) {
    // diagonal tile: exact 3-product from panel registers (self-sim bit-exact)
#pragma unroll
    for (int kt = 0; kt < 4; ++kt) {
      a = __builtin_amdgcn_mfma_f32_16x16x32_bf16(Ah[kt], Ah[kt], a, 0, 0, 0);
      a = __builtin_amdgcn_mfma_f32_16x16x32_bf16(Ah[kt], Al[kt], a, 0, 0, 0);
      a = __builtin_amdgcn_mfma_f32_16x16x32_bf16(Al[kt], Ah[kt], a, 0, 0, 0);
    }
  } else {
    const char* bp = (const char*)xf + (((size_t)ct * 256 + l) << 4);
#pragma unroll
    for (int kt = 0; kt < 4; ++kt) {
      bf16x8 Bh = *(const bf16x8*)(bp + (kt << 10));
      a = __builtin_amdgcn_mfma_f32_16x16x32_bf16(Bh, Ah[kt], a, 0, 0, 0);
      a = __builtin_amdgcn_mfma_f32_16x16x32_bf16(Bh, Al[kt], a, 0, 0, 0);
    }
  }
  return a;
}

__global__ __launch_bounds__(1024, 8)
void k_main(const float* __restrict__ x, const int* __restrict__ tgt,
            const float* __restrict__ marg, const float* __restrict__ wgt,
            const int* __restrict__ hm, float* __restrict__ out,
            const ushort* __restrict__ xf, float* __restrict__ lpart,
            unsigned* __restrict__ done)
{
  __shared__ float redA[16][16], redB[16][16], redC[16][16];
  __shared__ float finMn[16], finMx[16], lsRow[16];
  __shared__ float lsum[4];
  __shared__ unsigned lastf;

  const int tid = threadIdx.x;
  const int bid = blockIdx.x;
  const int w = tid >> 6, l = tid & 63;     // 16 waves; wave w owns cols [w*256, w*256+256)
  const int c = l & 15, g = l >> 4;
  const int i0 = bid * NROW;

  // ---- A fragments (16 panel rows, hi+lo): row i0+c, k = kt*32 + g*8 ----
  bf16x8 Ah[4], Al[4];
#pragma unroll
  for (int kt = 0; kt < 4; ++kt) {
    const float* ap = x + (i0 + c) * D + kt * 32 + g * 8;
    float4 v0 = *(const float4*)ap, v1 = *(const float4*)(ap + 4);
    int4 hp, lp;
    cvt8(v0, v1, hp, lp);
    Ah[kt] = *(bf16x8*)&hp;
    Al[kt] = *(bf16x8*)&lp;
  }

  const int trg = tgt[i0 + c];   // this lane's row target (scalar!)

  // ---- Pass A: stream tiles, scan per-row (scalar) min-pos / max-neg ----
  float mn = BIGV, mx = -BIGV;
#pragma unroll
  for (int ci = 0; ci < 16; ++ci) {
    const int ct = (w << 4) + ci;
    f32x4 a = tile_sim(xf, Ah, Al, ct, bid, l);
#pragma unroll
    for (int jj = 0; jj < 4; ++jj) {
      float s = a[jj];
      int tc = tgt[ct * 16 + g * 4 + jj];
      if (tc == trg) { if (s < 1.0f) mn = fminf(mn, s); }
      else             mx = fmaxf(mx, s);
    }
  }
  // reduce across the 4 g-groups (lanes c, c+16, c+32, c+48)
  mn = fminf(mn, __shfl_xor(mn, 16, 64));
  mn = fminf(mn, __shfl_xor(mn, 32, 64));
  mx = fmaxf(mx, __shfl_xor(mx, 16, 64));
  mx = fmaxf(mx, __shfl_xor(mx, 32, 64));
  if (l < 16) { redA[w][c] = mn; redB[w][c] = mx; }
  __syncthreads();
  if (tid < 16) {
    float a0 = BIGV, b0 = -BIGV;
#pragma unroll
    for (int w16 = 0; w16 < 16; ++w16) {
      a0 = fminf(a0, redA[w16][tid]);
      b0 = fmaxf(b0, redB[w16][tid]);
    }
    finMn[tid] = a0; finMx[tid] = b0;
  }
  __syncthreads();

  // ---- Pass B: recompute tiles, mine (scalar row state) ----
  const int mode = hm[0];
  float thrP, thrN, wp, wn;
  {
    float mg = marg[i0 + c], wt = wgt[i0 + c];
    if (mode == 1) {
      thrP = fminf(1.0f, finMx[c] + mg);   // same && s<1 && s<mxn+mg
      thrN = finMn[c] - mg;                // diff && s>mnp-mg
      wp = -2.f * wt; wn = 10.f * wt;
    } else {
      thrP = 1.0f; thrN = -BIGV;
      wp = -2.f; wn = 10.f;
    }
  }
  float ps = 0.f, ns = 0.f, cnt = 0.f;     // cnt = ap + 4096*an (exact <= 2^24)
#pragma unroll
  for (int ci = 0; ci < 16; ++ci) {
    const int ct = (w << 4) + ci;
    f32x4 a = tile_sim(xf, Ah, Al, ct, bid, l);
#pragma unroll
    for (int jj = 0; jj < 4; ++jj) {
      float s = a[jj];
      int tc = tgt[ct * 16 + g * 4 + jj];
      if (tc == trg) {
        if (s < thrP) { ps += __expf(wp * s); cnt += 1.f; }
      } else {
        if (s > thrN) { ns += __expf(wn * s); cnt += 4096.f; }
      }
    }
  }
  ps += __shfl_xor(ps, 16, 64); ps += __shfl_xor(ps, 32, 64);
  ns += __shfl_xor(ns, 16, 64); ns += __shfl_xor(ns, 32, 64);
  cnt += __shfl_xor(cnt, 16, 64); cnt += __shfl_xor(cnt, 32, 64);
  if (l < 16) { redA[w][c] = ps; redB[w][c] = ns; redC[w][c] = cnt; }
  __syncthreads();

  if (tid < 16) {
    float tps = 0.f, tns = 0.f, tcnt = 0.f;
#pragma unroll
    for (int w16 = 0; w16 < 16; ++w16) {
      tps += redA[w16][tid]; tns += redB[w16][tid]; tcnt += redC[w16][tid];
    }
    float an = floorf(tcnt * (1.0f / 4096.0f));
    float ap = tcnt - an * 4096.0f;
    float mg = marg[i0 + tid];
    float sP = (mode == 1) ? E1C  : __expf(1.f + 2.f * mg);
    float sN = (mode == 1) ? EM5C : __expf(-5.f + 10.f * mg);
    float loss_i = log1pf(tps * sP) + 0.2f * log1pf(tns * sN);
    if (mode == 1 && (ap + an) < 1.0f) { loss_i = 0.f; ap = 0.f; an = 0.f; }
    out[1 + i0 + tid]     = ap;
    out[1 + N + i0 + tid] = an;
    lsRow[tid] = loss_i;
  }
  __syncthreads();
  if (tid == 0) {
    float lb = 0.f;
#pragma unroll
    for (int r = 0; r < 16; ++r) lb += lsRow[r];
    stg(&lpart[bid], lb);
    asm volatile("s_waitcnt vmcnt(0)" ::: "memory");
    unsigned o = __hip_atomic_fetch_add(done, 1u, __ATOMIC_ACQ_REL, __HIP_MEMORY_SCOPE_AGENT);
    lastf = (o == (unsigned)(NBLKS - 1)) ? 1u : 0u;
  }
  __syncthreads();

  // ---- last block deterministically sums the 256 loss partials ----
  if (lastf) {
    float v = (tid < NBLKS) ? ldg1(&lpart[tid]) : 0.f;
#pragma unroll
    for (int msk = 32; msk; msk >>= 1) v += __shfl_down(v, msk, 64);
    if (tid < NBLKS && (tid & 63) == 0) lsum[tid >> 6] = v;
    __syncthreads();
    if (tid == 0) {
      float s = 0.f;
#pragma unroll
      for (int k2 = 0; k2 < 4; ++k2) s += lsum[k2];
      out[0] = s / (float)N;
    }
  }
}

extern "C" void kernel_launch(void* const* d_in, const int* in_sizes, int n_in,
                              void* d_out, int out_size, void* d_ws, size_t ws_size,
                              hipStream_t stream)
{
  (void)in_sizes; (void)n_in; (void)out_size; (void)ws_size;
  const float* x    = (const float*)d_in[0];
  const int*   tgt  = (const int*)d_in[1];
  const float* marg = (const float*)d_in[2];
  const float* wgt  = (const float*)d_in[3];
  const int*   hm   = (const int*)d_in[4];
  float* out = (float*)d_out;

  ushort*   xf    = (ushort*)d_ws;                          // 1 MB fragment-linear bf16-hi
  float*    lpart = (float*)((char*)d_ws + (1 << 20));      // 256 loss partials
  unsigned* done  = (unsigned*)(lpart + NBLKS);             // 1 counter

  k_conv<<<256, 256, 0, stream>>>(x, xf, done);
  k_main<<<NBLKS, 1024, 0, stream>>>(x, tgt, marg, wgt, hm, out, xf, lpart, done);
}

// Round 19
// 63.648 us; speedup vs baseline: 1.6835x; 1.6835x over previous
//
#include <hip/hip_runtime.h>
#include <math.h>

#define N 4096
#define D 128
#define NROW 16               // rows per block
#define NBLKS 256             // main-kernel grid (one 16-row panel per block)
#define BIGV 1e30f
#define E1C  2.718281828459045f     // e^1  (mode-1 pos post-scale)
#define EM5C 0.006737946999085467f  // e^-5 (mode-1 neg post-scale)

typedef __bf16 bf16x8 __attribute__((ext_vector_type(8)));
typedef float  f32x4  __attribute__((ext_vector_type(4)));

__device__ __forceinline__ void stg(float* p, float v) {
  __hip_atomic_store(p, v, __ATOMIC_RELAXED, __HIP_MEMORY_SCOPE_AGENT);
}
__device__ __forceinline__ float ldg1(const float* p) {
  return __hip_atomic_load((float*)p, __ATOMIC_RELAXED, __HIP_MEMORY_SCOPE_AGENT);
}

// split 8 f32 -> 8 bf16 hi + 8 bf16 lo (rne/rne; proven bit-exact path)
__device__ __forceinline__ void cvt8(float4 v0, float4 v1, int4& hp, int4& lp) {
  float vf[8] = {v0.x, v0.y, v0.z, v0.w, v1.x, v1.y, v1.z, v1.w};
  unsigned h[8], l[8];
#pragma unroll
  for (int i = 0; i < 8; ++i) {
    unsigned u = __float_as_uint(vf[i]);
    unsigned hr = (u + 0x7FFFu + ((u >> 16) & 1u)) >> 16;
    float hv = __uint_as_float(hr << 16);
    unsigned ul = __float_as_uint(vf[i] - hv);
    l[i] = (ul + 0x7FFFu + ((ul >> 16) & 1u)) >> 16;
    h[i] = hr;
  }
  hp = make_int4((int)(h[0] | (h[1] << 16)), (int)(h[2] | (h[3] << 16)),
                 (int)(h[4] | (h[5] << 16)), (int)(h[6] | (h[7] << 16)));
  lp = make_int4((int)(l[0] | (l[1] << 16)), (int)(l[2] | (l[3] << 16)),
                 (int)(l[4] | (l[5] << 16)), (int)(l[6] | (l[7] << 16)));
}
__device__ __forceinline__ void cvt8hi(float4 v0, float4 v1, int4& hp) {
  float vf[8] = {v0.x, v0.y, v0.z, v0.w, v1.x, v1.y, v1.z, v1.w};
  unsigned h[8];
#pragma unroll
  for (int i = 0; i < 8; ++i) {
    unsigned u = __float_as_uint(vf[i]);
    h[i] = (u + 0x7FFFu + ((u >> 16) & 1u)) >> 16;
  }
  hp = make_int4((int)(h[0] | (h[1] << 16)), (int)(h[2] | (h[3] << 16)),
                 (int)(h[4] | (h[5] << 16)), (int)(h[6] | (h[7] << 16)));
}

// ---- convert kernel: x -> bf16-hi in MFMA-fragment-linear order ----
// unit = ((C>>4)*4 + (k16>>2))*64 + (k16&3)*16 + (C&15); 16B per unit.
__global__ __launch_bounds__(256)
void k_conv(const float* __restrict__ x, ushort* __restrict__ xf, unsigned* done)
{
  if (blockIdx.x == 0 && threadIdx.x == 0)
    __hip_atomic_store(done, 0u, __ATOMIC_RELAXED, __HIP_MEMORY_SCOPE_AGENT);
  int gid = blockIdx.x * 256 + threadIdx.x;     // 65536 = 4096 C x 16 k16
  int C = gid >> 4, k16 = gid & 15;
  const float* ap = x + C * D + k16 * 8;
  float4 v0 = *(const float4*)ap, v1 = *(const float4*)(ap + 4);
  int4 hp;
  cvt8hi(v0, v1, hp);
  int unit = ((C >> 4) * 4 + (k16 >> 2)) * 64 + (k16 & 3) * 16 + (C & 15);
  *(int4*)((char*)xf + ((size_t)unit << 4)) = hp;
}

// Transposed-attribution tile: a[jj] = sim[row = i0 + (l&15)][col = ct*16 + (l>>4)*4 + jj]
// (mfma operand swap is free: A- and B-operand fragments share the same lane layout.)
__device__ __forceinline__ f32x4 tile_sim(const ushort* __restrict__ xf,
                                          const bf16x8 (&Ah)[4], const bf16x8 (&Al)[4],
                                          int ct, int bid, int l)
{
  f32x4 a = f32x4{0.f, 0.f, 0.f, 0.f};
  if (ct == bid) {
    // diagonal tile: exact 3-product from panel registers (self-sim bit-exact)
#pragma unroll
    for (int kt = 0; kt < 4; ++kt) {
      a = __builtin_amdgcn_mfma_f32_16x16x32_bf16(Ah[kt], Ah[kt], a, 0, 0, 0);
      a = __builtin_amdgcn_mfma_f32_16x16x32_bf16(Ah[kt], Al[kt], a, 0, 0, 0);
      a = __builtin_amdgcn_mfma_f32_16x16x32_bf16(Al[kt], Ah[kt], a, 0, 0, 0);
    }
  } else {
    const char* bp = (const char*)xf + (((size_t)ct * 256 + l) << 4);
#pragma unroll
    for (int kt = 0; kt < 4; ++kt) {
      bf16x8 Bh = *(const bf16x8*)(bp + (kt << 10));
      a = __builtin_amdgcn_mfma_f32_16x16x32_bf16(Bh, Ah[kt], a, 0, 0, 0);
      a = __builtin_amdgcn_mfma_f32_16x16x32_bf16(Bh, Al[kt], a, 0, 0, 0);
    }
  }
  return a;
}

__global__ __launch_bounds__(1024, 8)
void k_main(const float* __restrict__ x, const int* __restrict__ tgt,
            const float* __restrict__ marg, const float* __restrict__ wgt,
            const int* __restrict__ hm, float* __restrict__ out,
            const ushort* __restrict__ xf, float* __restrict__ lpart,
            unsigned* __restrict__ done)
{
  __shared__ float redA[16][16], redB[16][16], redC[16][16];
  __shared__ float finMn[16], finMx[16], lsRow[16];
  __shared__ float lsum[4];
  __shared__ unsigned lastf;

  const int tid = threadIdx.x;
  const int bid = blockIdx.x;
  const int w = tid >> 6, l = tid & 63;     // 16 waves; wave w owns cols [w*256, w*256+256)
  const int c = l & 15, g = l >> 4;
  const int i0 = bid * NROW;

  // ---- A fragments (16 panel rows, hi+lo): row i0+c, k = kt*32 + g*8 ----
  bf16x8 Ah[4], Al[4];
#pragma unroll
  for (int kt = 0; kt < 4; ++kt) {
    const float* ap = x + (i0 + c) * D + kt * 32 + g * 8;
    float4 v0 = *(const float4*)ap, v1 = *(const float4*)(ap + 4);
    int4 hp, lp;
    cvt8(v0, v1, hp, lp);
    Ah[kt] = *(bf16x8*)&hp;
    Al[kt] = *(bf16x8*)&lp;
  }

  const int trg = tgt[i0 + c];   // this lane's row target (scalar)

  // ---- Pass A: stream tiles (ROLLED loop: bounded reg pressure), scan min/max ----
  float mn = BIGV, mx = -BIGV;
#pragma unroll 1
  for (int ci = 0; ci < 16; ++ci) {
    const int ct = (w << 4) + ci;
    f32x4 a = tile_sim(xf, Ah, Al, ct, bid, l);
#pragma unroll
    for (int jj = 0; jj < 4; ++jj) {
      float s = a[jj];
      int tc = tgt[ct * 16 + g * 4 + jj];
      if (tc == trg) { if (s < 1.0f) mn = fminf(mn, s); }
      else             mx = fmaxf(mx, s);
    }
  }
  // reduce across the 4 g-groups (lanes c, c+16, c+32, c+48)
  mn = fminf(mn, __shfl_xor(mn, 16, 64));
  mn = fminf(mn, __shfl_xor(mn, 32, 64));
  mx = fmaxf(mx, __shfl_xor(mx, 16, 64));
  mx = fmaxf(mx, __shfl_xor(mx, 32, 64));
  if (l < 16) { redA[w][c] = mn; redB[w][c] = mx; }
  __syncthreads();
  if (tid < 16) {
    float a0 = BIGV, b0 = -BIGV;
#pragma unroll
    for (int w16 = 0; w16 < 16; ++w16) {
      a0 = fminf(a0, redA[w16][tid]);
      b0 = fmaxf(b0, redB[w16][tid]);
    }
    finMn[tid] = a0; finMx[tid] = b0;
  }
  __syncthreads();

  // ---- Pass B: recompute tiles (ROLLED loop), mine with scalar row state ----
  const int mode = hm[0];
  float thrP, thrN, wp, wn;
  {
    float mg = marg[i0 + c], wt = wgt[i0 + c];
    if (mode == 1) {
      thrP = fminf(1.0f, finMx[c] + mg);   // same && s<1 && s<mxn+mg
      thrN = finMn[c] - mg;                // diff && s>mnp-mg
      wp = -2.f * wt; wn = 10.f * wt;
    } else {
      thrP = 1.0f; thrN = -BIGV;
      wp = -2.f; wn = 10.f;
    }
  }
  float ps = 0.f, ns = 0.f, cnt = 0.f;     // cnt = ap + 4096*an (exact <= 2^24)
#pragma unroll 1
  for (int ci = 0; ci < 16; ++ci) {
    const int ct = (w << 4) + ci;
    f32x4 a = tile_sim(xf, Ah, Al, ct, bid, l);
#pragma unroll
    for (int jj = 0; jj < 4; ++jj) {
      float s = a[jj];
      int tc = tgt[ct * 16 + g * 4 + jj];
      if (tc == trg) {
        if (s < thrP) { ps += __expf(wp * s); cnt += 1.f; }
      } else {
        if (s > thrN) { ns += __expf(wn * s); cnt += 4096.f; }
      }
    }
  }
  ps += __shfl_xor(ps, 16, 64); ps += __shfl_xor(ps, 32, 64);
  ns += __shfl_xor(ns, 16, 64); ns += __shfl_xor(ns, 32, 64);
  cnt += __shfl_xor(cnt, 16, 64); cnt += __shfl_xor(cnt, 32, 64);
  if (l < 16) { redA[w][c] = ps; redB[w][c] = ns; redC[w][c] = cnt; }
  __syncthreads();

  if (tid < 16) {
    float tps = 0.f, tns = 0.f, tcnt = 0.f;
#pragma unroll
    for (int w16 = 0; w16 < 16; ++w16) {
      tps += redA[w16][tid]; tns += redB[w16][tid]; tcnt += redC[w16][tid];
    }
    float an = floorf(tcnt * (1.0f / 4096.0f));
    float ap = tcnt - an * 4096.0f;
    float mg = marg[i0 + tid];
    float sP = (mode == 1) ? E1C  : __expf(1.f + 2.f * mg);
    float sN = (mode == 1) ? EM5C : __expf(-5.f + 10.f * mg);
    float loss_i = log1pf(tps * sP) + 0.2f * log1pf(tns * sN);
    if (mode == 1 && (ap + an) < 1.0f) { loss_i = 0.f; ap = 0.f; an = 0.f; }
    out[1 + i0 + tid]     = ap;
    out[1 + N + i0 + tid] = an;
    lsRow[tid] = loss_i;
  }
  __syncthreads();
  if (tid == 0) {
    float lb = 0.f;
#pragma unroll
    for (int r = 0; r < 16; ++r) lb += lsRow[r];
    stg(&lpart[bid], lb);
    asm volatile("s_waitcnt vmcnt(0)" ::: "memory");
    unsigned o = __hip_atomic_fetch_add(done, 1u, __ATOMIC_ACQ_REL, __HIP_MEMORY_SCOPE_AGENT);
    lastf = (o == (unsigned)(NBLKS - 1)) ? 1u : 0u;
  }
  __syncthreads();

  // ---- last block deterministically sums the 256 loss partials ----
  if (lastf) {
    float v = (tid < NBLKS) ? ldg1(&lpart[tid]) : 0.f;
#pragma unroll
    for (int msk = 32; msk; msk >>= 1) v += __shfl_down(v, msk, 64);
    if (tid < NBLKS && (tid & 63) == 0) lsum[tid >> 6] = v;
    __syncthreads();
    if (tid == 0) {
      float s = 0.f;
#pragma unroll
      for (int k2 = 0; k2 < 4; ++k2) s += lsum[k2];
      out[0] = s / (float)N;
    }
  }
}

extern "C" void kernel_launch(void* const* d_in, const int* in_sizes, int n_in,
                              void* d_out, int out_size, void* d_ws, size_t ws_size,
                              hipStream_t stream)
{
  (void)in_sizes; (void)n_in; (void)out_size; (void)ws_size;
  const float* x    = (const float*)d_in[0];
  const int*   tgt  = (const int*)d_in[1];
  const float* marg = (const float*)d_in[2];
  const float* wgt  = (const float*)d_in[3];
  const int*   hm   = (const int*)d_in[4];
  float* out = (float*)d_out;

  ushort*   xf    = (ushort*)d_ws;                          // 1 MB fragment-linear bf16-hi
  float*    lpart = (float*)((char*)d_ws + (1 << 20));      // 256 loss partials
  unsigned* done  = (unsigned*)(lpart + NBLKS);             // 1 counter

  k_conv<<<256, 256, 0, stream>>>(x, xf, done);
  k_main<<<NBLKS, 1024, 0, stream>>>(x, tgt, marg, wgt, hm, out, xf, lpart, done);
}

// Round 20
// 43.130 us; speedup vs baseline: 2.4844x; 1.4757x over previous
//
#include <hip/hip_runtime.h>
#include <math.h>

#define N 4096
#define D 128
#define NROW 16               // rows per block
#define NBLKS 256             // main-kernel grid (one 16-row panel per block)
#define BIGV 1e30f

typedef __bf16 bf16x8 __attribute__((ext_vector_type(8)));
typedef float  f32x4  __attribute__((ext_vector_type(4)));
typedef __attribute__((address_space(3))) unsigned lds_u32;
typedef const __attribute__((address_space(1))) unsigned glb_u32;

__device__ __forceinline__ void stg(float* p, float v) {
  __hip_atomic_store(p, v, __ATOMIC_RELAXED, __HIP_MEMORY_SCOPE_AGENT);
}
__device__ __forceinline__ float ldg1(const float* p) {
  return __hip_atomic_load((float*)p, __ATOMIC_RELAXED, __HIP_MEMORY_SCOPE_AGENT);
}

// ---- DPP 16-lane reductions (VALU pipe, no LDS traffic): xor1, xor2, ror4, ror8 ----
template<int CTRL>
__device__ __forceinline__ float dppf(float v) {
  int r = __builtin_amdgcn_update_dpp(0, __float_as_int(v), CTRL, 0xF, 0xF, true);
  return __int_as_float(r);
}
__device__ __forceinline__ float rsum16(float v) {
  v += dppf<0xB1>(v);   // quad_perm [1,0,3,2]
  v += dppf<0x4E>(v);   // quad_perm [2,3,0,1]
  v += dppf<0x124>(v);  // row_ror:4
  v += dppf<0x128>(v);  // row_ror:8
  return v;
}
__device__ __forceinline__ float rmin16(float v) {
  v = fminf(v, dppf<0xB1>(v));
  v = fminf(v, dppf<0x4E>(v));
  v = fminf(v, dppf<0x124>(v));
  v = fminf(v, dppf<0x128>(v));
  return v;
}
__device__ __forceinline__ float rmax16(float v) {
  v = fmaxf(v, dppf<0xB1>(v));
  v = fmaxf(v, dppf<0x4E>(v));
  v = fmaxf(v, dppf<0x124>(v));
  v = fmaxf(v, dppf<0x128>(v));
  return v;
}

// split 8 f32 -> 8 bf16 hi + 8 bf16 lo (rne/rne; proven bit-exact path)
__device__ __forceinline__ void cvt8(float4 v0, float4 v1, int4& hp, int4& lp) {
  float vf[8] = {v0.x, v0.y, v0.z, v0.w, v1.x, v1.y, v1.z, v1.w};
  unsigned h[8], l[8];
#pragma unroll
  for (int i = 0; i < 8; ++i) {
    unsigned u = __float_as_uint(vf[i]);
    unsigned hr = (u + 0x7FFFu + ((u >> 16) & 1u)) >> 16;
    float hv = __uint_as_float(hr << 16);
    unsigned ul = __float_as_uint(vf[i] - hv);
    l[i] = (ul + 0x7FFFu + ((ul >> 16) & 1u)) >> 16;
    h[i] = hr;
  }
  hp = make_int4((int)(h[0] | (h[1] << 16)), (int)(h[2] | (h[3] << 16)),
                 (int)(h[4] | (h[5] << 16)), (int)(h[6] | (h[7] << 16)));
  lp = make_int4((int)(l[0] | (l[1] << 16)), (int)(l[2] | (l[3] << 16)),
                 (int)(l[4] | (l[5] << 16)), (int)(l[6] | (l[7] << 16)));
}
__device__ __forceinline__ void cvt8hi(float4 v0, float4 v1, int4& hp) {
  float vf[8] = {v0.x, v0.y, v0.z, v0.w, v1.x, v1.y, v1.z, v1.w};
  unsigned h[8];
#pragma unroll
  for (int i = 0; i < 8; ++i) {
    unsigned u = __float_as_uint(vf[i]);
    h[i] = (u + 0x7FFFu + ((u >> 16) & 1u)) >> 16;
  }
  hp = make_int4((int)(h[0] | (h[1] << 16)), (int)(h[2] | (h[3] << 16)),
                 (int)(h[4] | (h[5] << 16)), (int)(h[6] | (h[7] << 16)));
}

// ---- convert kernel: x -> bf16-hi in MFMA-fragment-linear order ----
// unit = ((C>>4)*4 + (k16>>2))*64 + (k16&3)*16 + (C&15); 16B per unit.
// Also resets the done-counter (replaces a separate memset dispatch).
__global__ __launch_bounds__(256)
void k_conv(const float* __restrict__ x, ushort* __restrict__ xf, unsigned* done)
{
  if (blockIdx.x == 0 && threadIdx.x == 0)
    __hip_atomic_store(done, 0u, __ATOMIC_RELAXED, __HIP_MEMORY_SCOPE_AGENT);
  int gid = blockIdx.x * 256 + threadIdx.x;     // 65536 = 4096 C x 16 k16
  int C = gid >> 4, k16 = gid & 15;
  const float* ap = x + C * D + k16 * 8;
  float4 v0 = *(const float4*)ap, v1 = *(const float4*)(ap + 4);
  int4 hp;
  cvt8hi(v0, v1, hp);
  int unit = ((C >> 4) * 4 + (k16 >> 2)) * 64 + (k16 & 3) * 16 + (C & 15);
  *(int4*)((char*)xf + ((size_t)unit << 4)) = hp;
}

#define VMCNT(n) asm volatile("s_waitcnt vmcnt(" #n ")" ::: "memory")

// stage tile ct_ (4 KB: 4 kt x 64 lanes x 16B) into wave-private buffer b_
#define STAGE(b_, ct_) do {                                                        \
    const char* gsrc_ = (const char*)xf + ((size_t)(ct_) << 12) + (l << 4);        \
    char* ldst_ = bbase + ((b_) << 12);                                            \
    _Pragma("unroll")                                                              \
    for (int kt_ = 0; kt_ < 4; ++kt_)                                              \
      __builtin_amdgcn_global_load_lds((glb_u32*)(gsrc_ + (kt_ << 10)),            \
                                       (lds_u32*)(ldst_ + (kt_ << 10)), 16, 0, 0); \
  } while (0)

__global__ __launch_bounds__(1024, 1)
void k_main(const float* __restrict__ x, const int* __restrict__ tgt,
            const float* __restrict__ marg, const float* __restrict__ wgt,
            const int* __restrict__ hm, float* __restrict__ out,
            const ushort* __restrict__ xf, float* __restrict__ lpart,
            unsigned* __restrict__ done)
{
  __shared__ __bf16 Bbuf[16][2][2048];          // 16 waves x 2 x 4 KB = 128 KB
  __shared__ float redA[16][16], redB[16][16], redC[16][16], redD[16][16];
  __shared__ float finMn[16], finMx[16], lsRow[16];
  __shared__ float lsum[4];
  __shared__ unsigned lastf;

  const int tid = threadIdx.x;
  const int bid = blockIdx.x;
  const int w = tid >> 6, l = tid & 63;     // 16 waves; wave w owns cols [w*256, w*256+256)
  const int c = l & 15, g = l >> 4;
  const int i0 = bid * NROW;
  char* bbase = (char*)&Bbuf[w][0][0];

  // per-thread row metadata (direct global; lanes with equal g broadcast-coalesce)
  int trow[4];
#pragma unroll
  for (int jj = 0; jj < 4; ++jj) trow[jj] = tgt[i0 + g * 4 + jj];

  // ---- A fragments (16 rows, hi+lo) in registers: row i0+c, k = kt*32 + g*8 ----
  bf16x8 Ah[4], Al[4];
#pragma unroll
  for (int kt = 0; kt < 4; ++kt) {
    const float* ap = x + (i0 + c) * D + kt * 32 + g * 8;
    float4 v0 = *(const float4*)ap, v1 = *(const float4*)(ap + 4);
    int4 hp, lp;
    cvt8(v0, v1, hp, lp);
    Ah[kt] = *(bf16x8*)&hp;
    Al[kt] = *(bf16x8*)&lp;
  }

  f32x4 acc[16];
#pragma unroll
  for (int ci = 0; ci < 16; ++ci) acc[ci] = f32x4{0.f, 0.f, 0.f, 0.f};

  float mn4[4], mx4[4];
#pragma unroll
  for (int jj = 0; jj < 4; ++jj) { mn4[jj] = BIGV; mx4[jj] = -BIGV; }

  // ---- K-loop: LDS dbuf + counted vmcnt(5) (4 stage + 1 tgt per tile), no barriers.
  //      Pass-1 (min/max scan) fused after each tile's MFMAs; fully unrolled so the
  //      compiler pipelines scan(ci) into stage(ci+1)'s latency window.
  STAGE(0, (w << 4));
  int tc_next = tgt[(w << 4) * 16 + c];
#pragma unroll
  for (int ci = 0; ci < 16; ++ci) {
    const int tc_cur = tc_next;
    if (ci + 1 < 16) {
      STAGE((ci + 1) & 1, (w << 4) + ci + 1);
      tc_next = tgt[((w << 4) + ci + 1) * 16 + c];
      VMCNT(5);                 // drains tile ci's 4 stages + tc_cur; next 5 in flight
    } else {
      VMCNT(0);
    }
    const int ct = (w << 4) + ci;
    if (ct == bid) {
      // diagonal tile: B-frags are the A-frag registers -> exact 3-product
#pragma unroll
      for (int kt = 0; kt < 4; ++kt) {
        acc[ci] = __builtin_amdgcn_mfma_f32_16x16x32_bf16(Ah[kt], Ah[kt], acc[ci], 0, 0, 0);
        acc[ci] = __builtin_amdgcn_mfma_f32_16x16x32_bf16(Ah[kt], Al[kt], acc[ci], 0, 0, 0);
        acc[ci] = __builtin_amdgcn_mfma_f32_16x16x32_bf16(Al[kt], Ah[kt], acc[ci], 0, 0, 0);
      }
    } else {
      const char* bp = bbase + ((ci & 1) << 12) + (l << 4);
#pragma unroll
      for (int kt = 0; kt < 4; ++kt) {
        bf16x8 Bh = *(const bf16x8*)(bp + (kt << 10));
        acc[ci] = __builtin_amdgcn_mfma_f32_16x16x32_bf16(Ah[kt], Bh, acc[ci], 0, 0, 0);
        acc[ci] = __builtin_amdgcn_mfma_f32_16x16x32_bf16(Al[kt], Bh, acc[ci], 0, 0, 0);
      }
    }
    // fused pass-1: acc[ci] is final for this tile
#pragma unroll
    for (int jj = 0; jj < 4; ++jj) {
      float s = acc[ci][jj];
      if (tc_cur == trow[jj]) { if (s < 1.0f) mn4[jj] = fminf(mn4[jj], s); }
      else                      mx4[jj] = fmaxf(mx4[jj], s);
    }
  }

  // ---- cross-lane (DPP) + cross-wave min/max reduction ----
#pragma unroll
  for (int jj = 0; jj < 4; ++jj) {
    mn4[jj] = rmin16(mn4[jj]);
    mx4[jj] = rmax16(mx4[jj]);
  }
  if (c == 0) {
#pragma unroll
    for (int jj = 0; jj < 4; ++jj) {
      redA[w][g * 4 + jj] = mn4[jj];
      redB[w][g * 4 + jj] = mx4[jj];
    }
  }
  __syncthreads();
  if (tid < 16) {
    float mn = BIGV, mx = -BIGV;
#pragma unroll
    for (int w16 = 0; w16 < 16; ++w16) {
      mn = fminf(mn, redA[w16][tid]);
      mx = fmaxf(mx, redB[w16][tid]);
    }
    finMn[tid] = mn; finMx[tid] = mx;
  }
  __syncthreads();

  // ---- mining epilogue over the same in-register acc ----
  const int mode = hm[0];
  float mnp[4], mxn[4], mg4[4], wt4[4];
  float ps4[4], ns4[4], ap4[4], an4[4];
#pragma unroll
  for (int jj = 0; jj < 4; ++jj) {
    int r = g * 4 + jj;
    mnp[jj] = finMn[r]; mxn[jj] = finMx[r];
    mg4[jj] = marg[i0 + r]; wt4[jj] = wgt[i0 + r];
    ps4[jj] = 0.f; ns4[jj] = 0.f; ap4[jj] = 0.f; an4[jj] = 0.f;
  }
#pragma unroll
  for (int ci = 0; ci < 16; ++ci) {
    int tc = tgt[((w << 4) + ci) * 16 + c];    // L1-hot (touched in K-loop)
#pragma unroll
    for (int jj = 0; jj < 4; ++jj) {
      float s = acc[ci][jj];
      bool same = (tc == trow[jj]);
      if (mode == 1) {
        float wsim = s * wt4[jj];
        if (same) {
          if (s < 1.0f && (mxn[jj] - s + mg4[jj] > 0.f)) {
            ps4[jj] += __expf(-2.f * (wsim - 0.5f)); ap4[jj] += 1.f;
          }
        } else {
          if (s + mg4[jj] - mnp[jj] > 0.f) {
            ns4[jj] += __expf(10.f * (wsim - 0.5f)); an4[jj] += 1.f;
          }
        }
      } else {
        if (same) {
          if (s < 1.0f) { ps4[jj] += __expf(-2.f * (s - 0.5f - mg4[jj])); ap4[jj] += 1.f; }
        } else {
          ns4[jj] += __expf(10.f * (s - 0.5f + mg4[jj])); an4[jj] += 1.f;
        }
      }
    }
  }
#pragma unroll
  for (int jj = 0; jj < 4; ++jj) {
    ps4[jj] = rsum16(ps4[jj]);
    ns4[jj] = rsum16(ns4[jj]);
    ap4[jj] = rsum16(ap4[jj]);
    an4[jj] = rsum16(an4[jj]);
  }
  if (c == 0) {
#pragma unroll
    for (int jj = 0; jj < 4; ++jj) {
      int r = g * 4 + jj;
      redA[w][r] = ps4[jj]; redB[w][r] = ns4[jj];
      redC[w][r] = ap4[jj]; redD[w][r] = an4[jj];
    }
  }
  __syncthreads();
  if (tid < 16) {
    float ps = 0.f, ns = 0.f, ap = 0.f, an = 0.f;
#pragma unroll
    for (int w16 = 0; w16 < 16; ++w16) {
      ps += redA[w16][tid]; ns += redB[w16][tid];
      ap += redC[w16][tid]; an += redD[w16][tid];
    }
    float loss_i = 1.0f * log1pf(ps) + 0.2f * log1pf(ns);
    if (mode == 1 && (ap + an) < 1.0f) { loss_i = 0.f; ap = 0.f; an = 0.f; }
    out[1 + i0 + tid]     = ap;
    out[1 + N + i0 + tid] = an;
    lsRow[tid] = loss_i;
  }
  __syncthreads();
  if (tid == 0) {
    float lb = 0.f;
#pragma unroll
    for (int r = 0; r < 16; ++r) lb += lsRow[r];
    stg(&lpart[bid], lb);
    asm volatile("s_waitcnt vmcnt(0)" ::: "memory");
    unsigned o = __hip_atomic_fetch_add(done, 1u, __ATOMIC_ACQ_REL, __HIP_MEMORY_SCOPE_AGENT);
    lastf = (o == (unsigned)(NBLKS - 1)) ? 1u : 0u;
  }
  __syncthreads();

  // ---- last block deterministically sums the 256 loss partials ----
  if (lastf) {
    float v = (tid < NBLKS) ? ldg1(&lpart[tid]) : 0.f;
#pragma unroll
    for (int msk = 32; msk; msk >>= 1) v += __shfl_down(v, msk, 64);
    if (tid < NBLKS && (tid & 63) == 0) lsum[tid >> 6] = v;
    __syncthreads();
    if (tid == 0) {
      float s = 0.f;
#pragma unroll
      for (int k2 = 0; k2 < 4; ++k2) s += lsum[k2];
      out[0] = s / (float)N;
    }
  }
}

extern "C" void kernel_launch(void* const* d_in, const int* in_sizes, int n_in,
                              void* d_out, int out_size, void* d_ws, size_t ws_size,
                              hipStream_t stream)
{
  (void)in_sizes; (void)n_in; (void)out_size; (void)ws_size;
  const float* x    = (const float*)d_in[0];
  const int*   tgt  = (const int*)d_in[1];
  const float* marg = (const float*)d_in[2];
  const float* wgt  = (const float*)d_in[3];
  const int*   hm   = (const int*)d_in[4];
  float* out = (float*)d_out;

  ushort*   xf    = (ushort*)d_ws;                          // 1 MB fragment-linear bf16-hi
  float*    lpart = (float*)((char*)d_ws + (1 << 20));      // 256 loss partials
  unsigned* done  = (unsigned*)(lpart + NBLKS);             // 1 counter

  k_conv<<<256, 256, 0, stream>>>(x, xf, done);
  k_main<<<NBLKS, 1024, 0, stream>>>(x, tgt, marg, wgt, hm, out, xf, lpart, done);
}